// Round 6
// baseline (53702.515 us; speedup 1.0000x reference)
//
#include <hip/hip_runtime.h>
#include <math.h>

// ESN reservoir recurrence, persistent-kernel, one-line mailbox protocol.
// x_{s+1} = 0.3*x_s + 0.7*tanh(0.9*W @ x_s + win0 * u[s])
// out[d][s-1001] = x_{s+1}[d] for s >= 1001   (out is 900 x 29999, row-major)
//
// Structure = round-0/5 harness-verified kernel (60 blocks x 256 thr, S1/S2
// barriers, one 64B publish line per block per step, system scope sc0 sc1 —
// rounds 1/2 established that anything weaker than sc0 sc1 on the poll side
// never observes the stores: L1 AND L2 must be bypassed, coherence point=LLC).
//
// Round-5 lesson: depth-2 polling with back-to-back issue still samples the
// mailbox in BURSTS (loads issued ~10cy apart return together) -> effective
// sampling period stays ~RT. This round de-bursts: 4 slots issued with
// s_sleep 3 (~192cy) spacing once per step; the rotation then self-sustains
// the phases (each check fires ~RT after its own issue). Sampling period
// ~RT/4 -> detection lag RT/2 -> ~RT/8. Hang-proof: infinite reissue of
// system-scope loads; counted waits pin the slot register via "+v" (proven
// in round 5); final vmcnt(0) drain pins all slots.
//
// Merged butterfly reduction (round-5 proven, bitwise identical) retained.

#define DIM        900
#define T_TOTAL    31000
#define DISCARD_P1 1001
#define OUT_T      29999
#define NBLK       60
#define ROWS_PB    15
#define NTHREADS   256
#define SR         0.9f
#define LEAKY      0.7f
#define RING_W     64

// Workspace (floats): [0..1023] parity-0 lines, [1024..2047] parity-1 lines.
// Line b = 16 floats: x[15 rows] + tag. Zero-init == state 0 with tag 0.0f.
#define XBUF_F    1024
#define WS_INIT_N 2048

typedef float vfloat4 __attribute__((ext_vector_type(4)));

__global__ void esn_init_ws(float* ws) {
    int i = threadIdx.x + blockIdx.x * blockDim.x;
    if (i < WS_INIT_N) ws[i] = 0.0f;
}

__device__ __forceinline__ void store_line16(float* p, vfloat4 v) {
    asm volatile("global_store_dwordx4 %0, %1, off sc0 sc1"
                 :: "v"(p), "v"(v) : "memory");
}

#define POLL_ISSUE(reg, srcp)                                        \
    asm volatile("global_load_dwordx4 %0, %1, off sc0 sc1"           \
                 : "=v"(reg) : "v"(srcp) : "memory")

__launch_bounds__(NTHREADS, 1)
__global__ void esn_persistent(const float* __restrict__ W,
                               const float* __restrict__ W_in,
                               const float* __restrict__ u,
                               float* __restrict__ out,
                               float* xbuf)
{
    __shared__ float x_lds[1024];                 // padded x: 60 lines x 16
    __shared__ float ring[ROWS_PB][RING_W + 1];   // output staging
    __shared__ float res[16];                     // this block's next line

    const int tid   = threadIdx.x;
    const int blk   = blockIdx.x;
    const int row0  = blk * ROWS_PB;
    const int wave  = tid >> 6;
    const int lane  = tid & 63;
    const int rbase = wave * 4;                   // rows rbase..rbase+3 (15=pad)

    for (int i = tid; i < 1024; i += NTHREADS) x_lds[i] = 0.0f;

    // W in registers over the PADDED 960-col layout: padded index p ->
    // source p>>4, offset p&15; offset 15 is the tag column -> W := 0.
    vfloat4 wreg[4][4];
    #pragma unroll
    for (int r = 0; r < 4; ++r) {
        const int row = rbase + r;
        #pragma unroll
        for (int k = 0; k < 4; ++k) {
            const int p = 4 * lane + 256 * k;
            vfloat4 v = (vfloat4)0.0f;
            if (row < ROWS_PB) {
                #pragma unroll
                for (int j = 0; j < 4; ++j) {
                    const int pp  = p + j;
                    const int off = pp & 15;
                    if (pp < 960 && off < 15) {
                        const int col = (pp >> 4) * 15 + off;
                        v[j] = SR * W[(size_t)(row0 + row) * DIM + col];
                    }
                }
            }
            wreg[r][k] = v;
        }
    }
    float win0r = 0.0f;
    if (lane < 4 && rbase + lane < ROWS_PB)
        win0r = W_in[(size_t)(row0 + rbase + lane) * DIM];   // column 0

    // Poll assignment: wave w covers source lines 15w..15w+14, 4 lanes/line.
    const int  sidx    = wave * 15 + (lane >> 2);   // valid for lane < 60
    const int  chunk   = lane & 3;
    const bool taglane = (lane < 60) && (chunk == 3);

    __syncthreads();   // x_lds zeros visible

    for (int s = 0; s < T_TOTAL; ++s) {
        const float ut  = u[s];
        const float tag = (float)s;
        const float* xin = xbuf + (size_t)(s & 1) * XBUF_F;

        // ---- phase-spaced 4-slot pipelined spin + x load ----
        if (lane < 60) {
            const float* src = xin + sidx * 16 + chunk * 4;
            float* dst = &x_lds[sidx * 16 + chunk * 4];
            vfloat4 v0, v1, v2, v3;
            POLL_ISSUE(v0, src);
            asm volatile("s_sleep 3" ::: "memory");   // ~192cy phase gap
            POLL_ISSUE(v1, src);
            asm volatile("s_sleep 3" ::: "memory");
            POLL_ISSUE(v2, src);
            asm volatile("s_sleep 3" ::: "memory");
            POLL_ISSUE(v3, src);
            for (;;) {
                asm volatile("s_waitcnt vmcnt(3)" : "+v"(v0) :: "memory");
                if (__all(!taglane || (v0.w == tag))) {
                    *reinterpret_cast<vfloat4*>(dst) = v0; break;
                }
                POLL_ISSUE(v0, src);
                asm volatile("s_waitcnt vmcnt(3)" : "+v"(v1) :: "memory");
                if (__all(!taglane || (v1.w == tag))) {
                    *reinterpret_cast<vfloat4*>(dst) = v1; break;
                }
                POLL_ISSUE(v1, src);
                asm volatile("s_waitcnt vmcnt(3)" : "+v"(v2) :: "memory");
                if (__all(!taglane || (v2.w == tag))) {
                    *reinterpret_cast<vfloat4*>(dst) = v2; break;
                }
                POLL_ISSUE(v2, src);
                asm volatile("s_waitcnt vmcnt(3)" : "+v"(v3) :: "memory");
                if (__all(!taglane || (v3.w == tag))) {
                    *reinterpret_cast<vfloat4*>(dst) = v3; break;
                }
                POLL_ISSUE(v3, src);
            }
            // Drain stragglers while pinning all slot registers so in-flight
            // loads can't clobber reused registers.
            asm volatile("s_waitcnt vmcnt(0)"
                         : "+v"(v0), "+v"(v1), "+v"(v2), "+v"(v3) :: "memory");
        }
        __syncthreads();   // S1: full padded x staged

        // ---- matvec: 4 rows/wave, W from registers, x via ds_read_b128 ----
        float a0 = 0.f, a1 = 0.f, a2 = 0.f, a3 = 0.f;
        #pragma unroll
        for (int k = 0; k < 4; ++k) {
            const vfloat4 xv =
                *reinterpret_cast<const vfloat4*>(&x_lds[4 * lane + 256 * k]);
            a0 += wreg[0][k].x * xv.x + wreg[0][k].y * xv.y
                + wreg[0][k].z * xv.z + wreg[0][k].w * xv.w;
            a1 += wreg[1][k].x * xv.x + wreg[1][k].y * xv.y
                + wreg[1][k].z * xv.z + wreg[1][k].w * xv.w;
            a2 += wreg[2][k].x * xv.x + wreg[2][k].y * xv.y
                + wreg[2][k].z * xv.z + wreg[2][k].w * xv.w;
            a3 += wreg[3][k].x * xv.x + wreg[3][k].y * xv.y
                + wreg[3][k].z * xv.z + wreg[3][k].w * xv.w;
        }

        // ---- merged butterfly (bitwise identical to 4 full trees) ----
        a0 += __shfl_xor(a0, 1, 64);
        a1 += __shfl_xor(a1, 1, 64);
        a2 += __shfl_xor(a2, 1, 64);
        a3 += __shfl_xor(a3, 1, 64);
        float m01 = (lane & 1) ? a1 : a0;
        float m23 = (lane & 1) ? a3 : a2;
        m01 += __shfl_xor(m01, 2, 64);
        m23 += __shfl_xor(m23, 2, 64);
        float m = (lane & 2) ? m23 : m01;
        #pragma unroll
        for (int off = 4; off < 64; off <<= 1)
            m += __shfl_xor(m, off, 64);
        // lane j (0..3): m = full dot product for row rbase+j

        // ---- epilogue: lanes 0..3 per wave finish one row each ----
        if (lane < 4) {
            const int r = rbase + lane;                 // 0..15
            if (r < ROWS_PB) {
                float z = m + win0r * ut;
                z = fminf(fmaxf(z, -9.0f), 9.0f);
                const float e  = __expf(2.0f * z);
                const float th = (e - 1.0f) / (e + 1.0f);
                const float xn = (1.0f - LEAKY) * x_lds[blk * 16 + r]
                               + LEAKY * th;
                res[r] = xn;
                if (s >= DISCARD_P1)
                    ring[r][(s - DISCARD_P1) & (RING_W - 1)] = xn;
            } else {
                res[15] = (float)(s + 1);               // tag for new state
            }
        }
        __syncthreads();   // S2: res complete

        // ---- publish: ONE 64B store carries 15 values + tag ----
        if (tid < 4) {
            const vfloat4 rv =
                *reinterpret_cast<const vfloat4*>(&res[4 * tid]);
            store_line16(xbuf + (size_t)((s + 1) & 1) * XBUF_F
                              + (size_t)blk * 16 + 4 * tid, rv);
        }

        // ---- output flush: after publish -> off the inter-block path ----
        if (s >= DISCARD_P1) {
            const int  c    = s - DISCARD_P1;
            const bool last = (s == T_TOTAL - 1);
            if ((c & (RING_W - 1)) == (RING_W - 1) || last) {
                const int len = (c & (RING_W - 1)) + 1;
                const int c0  = c - len + 1;
                if (len == RING_W) {
                    for (int i = tid; i < ROWS_PB * RING_W; i += NTHREADS) {
                        const int row = i >> 6, col = i & (RING_W - 1);
                        out[(size_t)(row0 + row) * OUT_T + c0 + col] =
                            ring[row][col];
                    }
                } else {
                    for (int i = tid; i < ROWS_PB * len; i += NTHREADS) {
                        const int row = i / len, col = i % len;
                        out[(size_t)(row0 + row) * OUT_T + c0 + col] =
                            ring[row][col];
                    }
                }
            }
        }
        // Next step's S1 orders this flush's ring reads vs. future ring writes.
    }
}

extern "C" void kernel_launch(void* const* d_in, const int* in_sizes, int n_in,
                              void* d_out, int out_size, void* d_ws, size_t ws_size,
                              hipStream_t stream) {
    const float* W    = (const float*)d_in[0];
    const float* W_in = (const float*)d_in[1];
    const float* u    = (const float*)d_in[2];
    float* out = (float*)d_out;
    float* ws  = (float*)d_ws;

    esn_init_ws<<<WS_INIT_N / 256, 256, 0, stream>>>(ws);
    esn_persistent<<<NBLK, NTHREADS, 0, stream>>>(W, W_in, u, out, ws);
}

// Round 7
// 49969.171 us; speedup vs baseline: 1.0747x; 1.0747x over previous
//
#include <hip/hip_runtime.h>
#include <math.h>

// ESN reservoir recurrence, persistent-kernel, one-line mailbox protocol.
// x_{s+1} = 0.3*x_s + 0.7*tanh(0.9*W @ x_s + win0 * u[s])
// out[d][s-1001] = x_{s+1}[d] for s >= 1001   (out is 900 x 29999, row-major)
//
// Structure = round-5 harness-verified kernel (60 blocks x 256 thr, S1/S2
// barriers, one 64B publish line per block per step, system scope sc0 sc1 —
// rounds 1/2 established anything weaker never observes the stores).
// Round-6 established phase-spread multi-slot polling is NEUTRAL ->
// consistent with same-address in-flight loads being MSHR-merged.
//
// THIS ROUND: relocate the straggler drain. Rounds 5/6 executed
// s_waitcnt vmcnt(0) immediately at detect -> if same-address loads are
// independent transactions that is a ~RT stall before S1 every step.
// Now the drain sits at the END of the step (only true hazard = slot
// register reuse by next step's poll issue), hiding it under the tail.
// Wave 0 drains with vmcnt(1) (its publish store, issued after all poll
// loads, may stay in flight - same leakage round 5 already had); waves
// 1-3 with vmcnt(0). s_waitcnt is wave-wide scalar -> counts wave-uniform.
// Slot registers stay pinned across the tail via "+v" on the drain.
//
// Discriminating experiment: win ~3-6ms => independent transactions
// (drain was stalling). Neutral => MSHR merge confirmed; next lever is
// structural (per-wave chunk flags), not polling.

#define DIM        900
#define T_TOTAL    31000
#define DISCARD_P1 1001
#define OUT_T      29999
#define NBLK       60
#define ROWS_PB    15
#define NTHREADS   256
#define SR         0.9f
#define LEAKY      0.7f
#define RING_W     64

// Workspace (floats): [0..1023] parity-0 lines, [1024..2047] parity-1 lines.
// Line b = 16 floats: x[15 rows] + tag. Zero-init == state 0 with tag 0.0f.
#define XBUF_F    1024
#define WS_INIT_N 2048

typedef float vfloat4 __attribute__((ext_vector_type(4)));

__global__ void esn_init_ws(float* ws) {
    int i = threadIdx.x + blockIdx.x * blockDim.x;
    if (i < WS_INIT_N) ws[i] = 0.0f;
}

__device__ __forceinline__ void store_line16(float* p, vfloat4 v) {
    asm volatile("global_store_dwordx4 %0, %1, off sc0 sc1"
                 :: "v"(p), "v"(v) : "memory");
}

#define POLL_ISSUE(reg, srcp)                                        \
    asm volatile("global_load_dwordx4 %0, %1, off sc0 sc1"           \
                 : "=v"(reg) : "v"(srcp) : "memory")

__launch_bounds__(NTHREADS, 1)
__global__ void esn_persistent(const float* __restrict__ W,
                               const float* __restrict__ W_in,
                               const float* __restrict__ u,
                               float* __restrict__ out,
                               float* xbuf)
{
    __shared__ float x_lds[1024];                 // padded x: 60 lines x 16
    __shared__ float ring[ROWS_PB][RING_W + 1];   // output staging
    __shared__ float res[16];                     // this block's next line

    const int tid   = threadIdx.x;
    const int blk   = blockIdx.x;
    const int row0  = blk * ROWS_PB;
    const int wave  = tid >> 6;
    const int lane  = tid & 63;
    const int rbase = wave * 4;                   // rows rbase..rbase+3 (15=pad)

    for (int i = tid; i < 1024; i += NTHREADS) x_lds[i] = 0.0f;

    // W in registers over the PADDED 960-col layout: padded index p ->
    // source p>>4, offset p&15; offset 15 is the tag column -> W := 0.
    vfloat4 wreg[4][4];
    #pragma unroll
    for (int r = 0; r < 4; ++r) {
        const int row = rbase + r;
        #pragma unroll
        for (int k = 0; k < 4; ++k) {
            const int p = 4 * lane + 256 * k;
            vfloat4 v = (vfloat4)0.0f;
            if (row < ROWS_PB) {
                #pragma unroll
                for (int j = 0; j < 4; ++j) {
                    const int pp  = p + j;
                    const int off = pp & 15;
                    if (pp < 960 && off < 15) {
                        const int col = (pp >> 4) * 15 + off;
                        v[j] = SR * W[(size_t)(row0 + row) * DIM + col];
                    }
                }
            }
            wreg[r][k] = v;
        }
    }
    float win0r = 0.0f;
    if (lane < 4 && rbase + lane < ROWS_PB)
        win0r = W_in[(size_t)(row0 + rbase + lane) * DIM];   // column 0

    // Poll assignment: wave w covers source lines 15w..15w+14, 4 lanes/line.
    const int  sidx    = wave * 15 + (lane >> 2);   // valid for lane < 60
    const int  chunk   = lane & 3;
    const bool taglane = (lane < 60) && (chunk == 3);

    vfloat4 v0, v1;                 // poll slots, live across the step tail

    __syncthreads();   // x_lds zeros visible

    for (int s = 0; s < T_TOTAL; ++s) {
        const float ut  = u[s];
        const float tag = (float)s;
        const float* xin = xbuf + (size_t)(s & 1) * XBUF_F;

        // ---- depth-2 pipelined spin + x load (no drain at detect) ----
        if (lane < 60) {
            const float* src = xin + sidx * 16 + chunk * 4;
            float* dst = &x_lds[sidx * 16 + chunk * 4];
            POLL_ISSUE(v0, src);
            for (;;) {
                POLL_ISSUE(v1, src);
                asm volatile("s_waitcnt vmcnt(1)"        // v0 ready
                             : "+v"(v0) :: "memory");
                if (__all(!taglane || (v0.w == tag))) {
                    *reinterpret_cast<vfloat4*>(dst) = v0;
                    break;
                }
                POLL_ISSUE(v0, src);
                asm volatile("s_waitcnt vmcnt(1)"        // v1 ready
                             : "+v"(v1) :: "memory");
                if (__all(!taglane || (v1.w == tag))) {
                    *reinterpret_cast<vfloat4*>(dst) = v1;
                    break;
                }
            }
            // straggler (1 load) stays in flight through the tail
        }
        __syncthreads();   // S1: full padded x staged

        // ---- matvec: 4 rows/wave, W from registers, x via ds_read_b128 ----
        float a0 = 0.f, a1 = 0.f, a2 = 0.f, a3 = 0.f;
        #pragma unroll
        for (int k = 0; k < 4; ++k) {
            const vfloat4 xv =
                *reinterpret_cast<const vfloat4*>(&x_lds[4 * lane + 256 * k]);
            a0 += wreg[0][k].x * xv.x + wreg[0][k].y * xv.y
                + wreg[0][k].z * xv.z + wreg[0][k].w * xv.w;
            a1 += wreg[1][k].x * xv.x + wreg[1][k].y * xv.y
                + wreg[1][k].z * xv.z + wreg[1][k].w * xv.w;
            a2 += wreg[2][k].x * xv.x + wreg[2][k].y * xv.y
                + wreg[2][k].z * xv.z + wreg[2][k].w * xv.w;
            a3 += wreg[3][k].x * xv.x + wreg[3][k].y * xv.y
                + wreg[3][k].z * xv.z + wreg[3][k].w * xv.w;
        }

        // ---- merged butterfly (bitwise identical to 4 full trees) ----
        a0 += __shfl_xor(a0, 1, 64);
        a1 += __shfl_xor(a1, 1, 64);
        a2 += __shfl_xor(a2, 1, 64);
        a3 += __shfl_xor(a3, 1, 64);
        float m01 = (lane & 1) ? a1 : a0;
        float m23 = (lane & 1) ? a3 : a2;
        m01 += __shfl_xor(m01, 2, 64);
        m23 += __shfl_xor(m23, 2, 64);
        float m = (lane & 2) ? m23 : m01;
        #pragma unroll
        for (int off = 4; off < 64; off <<= 1)
            m += __shfl_xor(m, off, 64);
        // lane j (0..3): m = full dot product for row rbase+j

        // ---- epilogue: lanes 0..3 per wave finish one row each ----
        if (lane < 4) {
            const int r = rbase + lane;                 // 0..15
            if (r < ROWS_PB) {
                float z = m + win0r * ut;
                z = fminf(fmaxf(z, -9.0f), 9.0f);
                const float e  = __expf(2.0f * z);
                const float th = (e - 1.0f) / (e + 1.0f);
                const float xn = (1.0f - LEAKY) * x_lds[blk * 16 + r]
                               + LEAKY * th;
                res[r] = xn;
                if (s >= DISCARD_P1)
                    ring[r][(s - DISCARD_P1) & (RING_W - 1)] = xn;
            } else {
                res[15] = (float)(s + 1);               // tag for new state
            }
        }
        __syncthreads();   // S2: res complete

        // ---- publish: ONE 64B store carries 15 values + tag ----
        if (tid < 4) {
            const vfloat4 rv =
                *reinterpret_cast<const vfloat4*>(&res[4 * tid]);
            store_line16(xbuf + (size_t)((s + 1) & 1) * XBUF_F
                              + (size_t)blk * 16 + 4 * tid, rv);
        }

        // ---- output flush: after publish -> off the inter-block path ----
        if (s >= DISCARD_P1) {
            const int  c    = s - DISCARD_P1;
            const bool last = (s == T_TOTAL - 1);
            if ((c & (RING_W - 1)) == (RING_W - 1) || last) {
                const int len = (c & (RING_W - 1)) + 1;
                const int c0  = c - len + 1;
                if (len == RING_W) {
                    for (int i = tid; i < ROWS_PB * RING_W; i += NTHREADS) {
                        const int row = i >> 6, col = i & (RING_W - 1);
                        out[(size_t)(row0 + row) * OUT_T + c0 + col] =
                            ring[row][col];
                    }
                } else {
                    for (int i = tid; i < ROWS_PB * len; i += NTHREADS) {
                        const int row = i / len, col = i % len;
                        out[(size_t)(row0 + row) * OUT_T + c0 + col] =
                            ring[row][col];
                    }
                }
            }
        }

        // ---- relocated drain: only hazard is next step's slot reuse ----
        // Wave 0's publish store (and flush stores) are NEWER than the
        // straggler load, so counted waits still guarantee the straggler
        // is done. Wave 0 leaves its publish store in flight (vmcnt(1),
        // same leakage round 5 had); waves 1-3 fully drain.
        if (wave == 0)
            asm volatile("s_waitcnt vmcnt(1)"
                         : "+v"(v0), "+v"(v1) :: "memory");
        else
            asm volatile("s_waitcnt vmcnt(0)"
                         : "+v"(v0), "+v"(v1) :: "memory");
        // Next step's S1 orders this flush's ring reads vs. future ring writes.
    }
}

extern "C" void kernel_launch(void* const* d_in, const int* in_sizes, int n_in,
                              void* d_out, int out_size, void* d_ws, size_t ws_size,
                              hipStream_t stream) {
    const float* W    = (const float*)d_in[0];
    const float* W_in = (const float*)d_in[1];
    const float* u    = (const float*)d_in[2];
    float* out = (float*)d_out;
    float* ws  = (float*)d_ws;

    esn_init_ws<<<WS_INIT_N / 256, 256, 0, stream>>>(ws);
    esn_persistent<<<NBLK, NTHREADS, 0, stream>>>(W, W_in, u, out, ws);
}